// Round 7
// baseline (261.446 us; speedup 1.0000x reference)
//
#include <hip/hip_runtime.h>
#include <hip/hip_bf16.h>
#include <stdint.h>

#define NUM_NODES 100000
#define NUM_EDGES 50000
#define NUM_CONN  800000
#define IN_DIM    256
#define HIDDEN    128
#define EDGE_DIM  17
#define PAD       64

typedef __bf16 bf16x8 __attribute__((ext_vector_type(8)));
typedef float  f32x4  __attribute__((ext_vector_type(4)));

// ---------------- ws layout ----------------
// P     : bf16 [NUM_NODES][HIDDEN]   25,600,000 B @ 0
// counts: int  [NUM_EDGES]              200,000 B @ 25,600,000
// slots : int  [NUM_EDGES][PAD]      12,800,000 B @ 25,800,000
// W1F   : bf16 frag-major [8][8][64][8]  65,536 B @ 38,600,000
// W2F   : bf16 frag-major [4][2][64][8]   8,192 B @ 38,665,536

// Zero counts + pack W1/W2 into MFMA B-fragment-major bf16 (one launch).
__global__ void prep_kernel(const float* __restrict__ W1, const float* __restrict__ W2,
                            __bf16* __restrict__ w1f, __bf16* __restrict__ w2f,
                            int* __restrict__ counts) {
    int i = blockIdx.x * 256 + threadIdx.x;   // grid 196*256 = 50176
    if (i < NUM_EDGES) counts[i] = 0;
    if (i < 4096) {            // W1F[kc2][t][lane][ki]
        int lane = i & 63, t = (i >> 6) & 7, kc2 = i >> 9;
        int m = lane & 15, q = lane >> 4;
        int n = t * 16 + m;
        int kbase = kc2 * 32 + q * 8;
        __bf16* dst = w1f + (size_t)i * 8;
        #pragma unroll
        for (int ki = 0; ki < 8; ++ki)
            dst[ki] = (__bf16)W1[(size_t)(kbase + ki) * HIDDEN + n];
    } else if (i < 4608) {     // W2F[ks][t][lane][ki], n>=17 zero-padded
        int f = i - 4096;
        int lane = f & 63, t = (f >> 6) & 1, ks = f >> 7;
        int m = lane & 15, q = lane >> 4;
        int n = t * 16 + m;
        int kbase = ks * 32 + q * 8;
        __bf16* dst = w2f + (size_t)f * 8;
        #pragma unroll
        for (int ki = 0; ki < 8; ++ki)
            dst[ki] = (n < EDGE_DIM) ? (__bf16)W2[(size_t)(kbase + ki) * EDGE_DIM + n]
                                     : (__bf16)0.0f;
    }
}

// Fused bucket + proj.
// blockIdx % 9 == 4 -> bucket role (391 blocks, 8 conns/thread, 8 atomic chains in flight)
// else              -> proj role  (3128 blocks; 256 rows x 64 cols each, 32 KB LDS)
#define FRONT_BLOCKS 3519
__global__ __launch_bounds__(256, 4) void front_kernel(const int* __restrict__ idx,
        int stride, int* __restrict__ counts, int* __restrict__ slots,
        const float* __restrict__ nf, const __bf16* __restrict__ w1f,
        __bf16* __restrict__ pbf) {
    __shared__ __align__(16) __bf16 lds_w[16384];   // 32 KB: half the n-tiles
    if (blockIdx.x % 9 == 4) {
        // ---- bucket role ----
        int b = blockIdx.x / 9;
        long c0 = ((long)b * 256 + threadIdx.x) * 8;
        if (c0 < NUM_CONN) {
            int nd[8], ed[8];
            if (stride == 2) {   // int64: int4 = 2 elems (lo words .x/.z)
                #pragma unroll
                for (int k = 0; k < 4; ++k) {
                    int4 vn = ((const int4*)idx)[c0 / 2 + k];
                    int4 ve = ((const int4*)(idx + 2 * NUM_CONN))[c0 / 2 + k];
                    nd[2 * k] = vn.x; nd[2 * k + 1] = vn.z;
                    ed[2 * k] = ve.x; ed[2 * k + 1] = ve.z;
                }
            } else {
                #pragma unroll
                for (int k = 0; k < 8; ++k) {
                    nd[k] = idx[c0 + k];
                    ed[k] = idx[NUM_CONN + c0 + k];
                }
            }
            int pos[8];
            #pragma unroll
            for (int k = 0; k < 8; ++k) pos[k] = atomicAdd(&counts[ed[k]], 1);
            #pragma unroll
            for (int k = 0; k < 8; ++k)
                if (pos[k] < PAD) slots[(size_t)ed[k] * PAD + pos[k]] = nd[k];
        }
        return;
    }
    // ---- proj role: 256 rows x 64 cols per block ----
    const int p = blockIdx.x - blockIdx.x / 9 - (blockIdx.x % 9 > 4 ? 1 : 0);
    const int rt = p >> 1;          // row-tile 0..1563 (>=1563 fully clamped/guarded)
    const int ch = p & 1;           // column half
    {
        const uint4* src = (const uint4*)w1f;
        uint4* dst = (uint4*)lds_w;
        #pragma unroll
        for (int i = threadIdx.x; i < 2048; i += 256) {
            int kc2 = i >> 8, tt = (i >> 6) & 3, lane = i & 63;
            dst[i] = src[(kc2 * 8 + ch * 4 + tt) * 64 + lane];
        }
    }
    __syncthreads();

    const int wave = threadIdx.x >> 6;
    const int lane = threadIdx.x & 63;
    const int m = lane & 15, q = lane >> 4;
    const int rowbase = rt * 256 + wave * 64;
    const bf16x8* frag = (const bf16x8*)lds_w;

    f32x4 acc[4][4];
    #pragma unroll
    for (int mt = 0; mt < 4; ++mt)
        #pragma unroll
        for (int tt = 0; tt < 4; ++tt) acc[mt][tt] = (f32x4){0.f, 0.f, 0.f, 0.f};

    const float* ap[4];
    #pragma unroll
    for (int mt = 0; mt < 4; ++mt) {
        int r = rowbase + mt * 16 + m;
        if (r >= NUM_NODES) r = NUM_NODES - 1;
        ap[mt] = nf + (size_t)r * IN_DIM + q * 8;
    }

    #pragma unroll
    for (int kc2 = 0; kc2 < 8; ++kc2) {
        bf16x8 b[4];
        #pragma unroll
        for (int tt = 0; tt < 4; ++tt) b[tt] = frag[(kc2 * 4 + tt) * 64 + lane];
        #pragma unroll
        for (int mt = 0; mt < 4; ++mt) {
            float4 f0 = *(const float4*)(ap[mt] + kc2 * 32);
            float4 f1 = *(const float4*)(ap[mt] + kc2 * 32 + 4);
            bf16x8 a;
            a[0] = (__bf16)f0.x; a[1] = (__bf16)f0.y;
            a[2] = (__bf16)f0.z; a[3] = (__bf16)f0.w;
            a[4] = (__bf16)f1.x; a[5] = (__bf16)f1.y;
            a[6] = (__bf16)f1.z; a[7] = (__bf16)f1.w;
            #pragma unroll
            for (int tt = 0; tt < 4; ++tt)
                acc[mt][tt] = __builtin_amdgcn_mfma_f32_16x16x32_bf16(a, b[tt], acc[mt][tt], 0, 0, 0);
        }
    }

    #pragma unroll
    for (int mt = 0; mt < 4; ++mt) {
        int ob = rowbase + mt * 16 + q * 4;
        #pragma unroll
        for (int tt = 0; tt < 4; ++tt) {
            int col = (ch * 4 + tt) * 16 + m;
            #pragma unroll
            for (int r = 0; r < 4; ++r) {
                int orow = ob + r;
                if (orow < NUM_NODES)
                    pbf[(size_t)orow * HIDDEN + col] = (__bf16)acc[mt][tt][r];
            }
        }
    }
}

// 4 edges/wave, 16 lanes/edge gather + LN + ReLU, then the block's 16 edges
// (= one MFMA tile) go through LDS and wave 0 computes out = r@W2 + b2.
__global__ __launch_bounds__(256) void edge_kernel(const uint4* __restrict__ p4,
        const int* __restrict__ counts, const int* __restrict__ slots,
        const float* __restrict__ b1, const float* __restrict__ ln_g,
        const float* __restrict__ ln_b, const __bf16* __restrict__ w2f,
        const float* __restrict__ b2, float* __restrict__ out) {
    __shared__ __align__(16) uint4 lds_r[256];   // 16 edges x 128 bf16 = 4 KB
    const int wave = threadIdx.x >> 6;
    const int lane = threadIdx.x & 63;
    const int g = lane & 15, ge = lane >> 4;
    const int el = wave * 4 + ge;                 // edge-local 0..15
    const int e = blockIdx.x * 16 + el;

    const int c = counts[e];
    const int cc = c < PAD ? c : PAD;
    const float inv = 1.0f / (float)(c > 0 ? c : 1);

    float acc[8];
    #pragma unroll
    for (int d = 0; d < 8; ++d) acc[d] = 0.f;

    for (int c0 = 0; c0 < cc; c0 += 16) {
        int slv = slots[(size_t)e * PAD + c0 + g];
        int lim = cc - c0; if (lim > 16) lim = 16;
        if (lim == 16) {
            #pragma unroll
            for (int k0 = 0; k0 < 16; k0 += 4) {
                uint4 u[4];
                #pragma unroll
                for (int k = 0; k < 4; ++k) {
                    int nd = __shfl(slv, ge * 16 + k0 + k, 64);
                    u[k] = p4[(size_t)nd * 16 + g];
                }
                #pragma unroll
                for (int k = 0; k < 4; ++k) {
                    acc[0] += __uint_as_float(u[k].x << 16);
                    acc[1] += __uint_as_float(u[k].x & 0xffff0000u);
                    acc[2] += __uint_as_float(u[k].y << 16);
                    acc[3] += __uint_as_float(u[k].y & 0xffff0000u);
                    acc[4] += __uint_as_float(u[k].z << 16);
                    acc[5] += __uint_as_float(u[k].z & 0xffff0000u);
                    acc[6] += __uint_as_float(u[k].w << 16);
                    acc[7] += __uint_as_float(u[k].w & 0xffff0000u);
                }
            }
        } else {
            for (int k0 = 0; k0 < lim; k0 += 4) {
                uint4 u[4];
                unsigned okm[4];
                #pragma unroll
                for (int k = 0; k < 4; ++k) {
                    int nd = __shfl(slv, ge * 16 + k0 + k, 64);
                    nd = ((unsigned)nd < NUM_NODES) ? nd : 0;
                    u[k] = p4[(size_t)nd * 16 + g];
                    okm[k] = (k0 + k < lim) ? 0xffffffffu : 0u;
                }
                #pragma unroll
                for (int k = 0; k < 4; ++k) {
                    uint4 v = u[k];
                    v.x &= okm[k]; v.y &= okm[k]; v.z &= okm[k]; v.w &= okm[k];
                    acc[0] += __uint_as_float(v.x << 16);
                    acc[1] += __uint_as_float(v.x & 0xffff0000u);
                    acc[2] += __uint_as_float(v.y << 16);
                    acc[3] += __uint_as_float(v.y & 0xffff0000u);
                    acc[4] += __uint_as_float(v.z << 16);
                    acc[5] += __uint_as_float(v.z & 0xffff0000u);
                    acc[6] += __uint_as_float(v.w << 16);
                    acc[7] += __uint_as_float(v.w & 0xffff0000u);
                }
            }
        }
    }

    float4 bA = ((const float4*)b1)[2 * g];
    float4 bB = ((const float4*)b1)[2 * g + 1];
    float h[8];
    h[0] = acc[0] * inv + bA.x; h[1] = acc[1] * inv + bA.y;
    h[2] = acc[2] * inv + bA.z; h[3] = acc[3] * inv + bA.w;
    h[4] = acc[4] * inv + bB.x; h[5] = acc[5] * inv + bB.y;
    h[6] = acc[6] * inv + bB.z; h[7] = acc[7] * inv + bB.w;

    float s = 0.f;
    #pragma unroll
    for (int d = 0; d < 8; ++d) s += h[d];
    #pragma unroll
    for (int off = 8; off > 0; off >>= 1) s += __shfl_xor(s, off, 64);
    float mu = s * (1.0f / 128.0f);

    float dv[8], vv = 0.f;
    #pragma unroll
    for (int d = 0; d < 8; ++d) { dv[d] = h[d] - mu; vv += dv[d] * dv[d]; }
    #pragma unroll
    for (int off = 8; off > 0; off >>= 1) vv += __shfl_xor(vv, off, 64);
    float rs = rsqrtf(vv * (1.0f / 128.0f) + 1e-5f);

    float4 gA = ((const float4*)ln_g)[2 * g];
    float4 gB = ((const float4*)ln_g)[2 * g + 1];
    float4 eA = ((const float4*)ln_b)[2 * g];
    float4 eB = ((const float4*)ln_b)[2 * g + 1];
    float gg[8] = {gA.x, gA.y, gA.z, gA.w, gB.x, gB.y, gB.z, gB.w};
    float ee[8] = {eA.x, eA.y, eA.z, eA.w, eB.x, eB.y, eB.z, eB.w};
    union { __bf16 b[8]; uint4 u; } pk;
    #pragma unroll
    for (int d = 0; d < 8; ++d) {
        float r = dv[d] * rs * gg[d] + ee[d];
        pk.b[d] = (__bf16)(r > 0.f ? r : 0.f);
    }
    lds_r[el * 16 + g] = pk.u;
    __syncthreads();

    if (wave == 0) {   // out tile: [16 edges x 128] @ [128 x 32pad]
        const int m = lane & 15, q = lane >> 4;
        const __bf16* lr = (const __bf16*)lds_r;
        const bf16x8* fw = (const bf16x8*)w2f;
        f32x4 a0 = (f32x4){0.f, 0.f, 0.f, 0.f};
        f32x4 a1 = (f32x4){0.f, 0.f, 0.f, 0.f};
        #pragma unroll
        for (int ks = 0; ks < 4; ++ks) {
            bf16x8 a = *(const bf16x8*)(lr + m * 128 + ks * 32 + q * 8);
            a0 = __builtin_amdgcn_mfma_f32_16x16x32_bf16(a, fw[(ks * 2 + 0) * 64 + lane], a0, 0, 0, 0);
            a1 = __builtin_amdgcn_mfma_f32_16x16x32_bf16(a, fw[(ks * 2 + 1) * 64 + lane], a1, 0, 0, 0);
        }
        int rowb = blockIdx.x * 16 + q * 4;
        float bm = b2[m];
        float b16 = b2[16];
        #pragma unroll
        for (int r = 0; r < 4; ++r) {
            out[(size_t)(rowb + r) * EDGE_DIM + m] = a0[r] + bm;
            if (m == 0) out[(size_t)(rowb + r) * EDGE_DIM + 16] = a1[r] + b16;
        }
    }
}

extern "C" void kernel_launch(void* const* d_in, const int* in_sizes, int n_in,
                              void* d_out, int out_size, void* d_ws, size_t ws_size,
                              hipStream_t stream) {
    const float* nf  = (const float*)d_in[0];
    const int*   idx = (const int*)d_in[1];
    const float* W1  = (const float*)d_in[2];
    const float* b1  = (const float*)d_in[3];
    const float* g   = (const float*)d_in[4];
    const float* be  = (const float*)d_in[5];
    const float* W2  = (const float*)d_in[6];
    const float* b2  = (const float*)d_in[7];
    float* out = (float*)d_out;

    char* ws = (char*)d_ws;
    __bf16* P      = (__bf16*)ws;
    int*    counts = (int*)(ws + 25600000);
    int*    slots  = (int*)(ws + 25800000);
    __bf16* W1F    = (__bf16*)(ws + 38600000);
    __bf16* W2F    = (__bf16*)(ws + 38665536);

    int stride = (in_sizes[1] == 2 * NUM_CONN) ? 1 : 2;

    prep_kernel<<<196, 256, 0, stream>>>(W1, W2, W1F, W2F, counts);
    front_kernel<<<FRONT_BLOCKS, 256, 0, stream>>>(idx, stride, counts, slots, nf, W1F, P);
    edge_kernel<<<NUM_EDGES / 16, 256, 0, stream>>>((const uint4*)P, counts, slots,
                                                    b1, g, be, W2F, b2, out);
}

// Round 8
// 257.797 us; speedup vs baseline: 1.0142x; 1.0142x over previous
//
#include <hip/hip_runtime.h>
#include <hip/hip_bf16.h>
#include <stdint.h>

#define NUM_NODES 100000
#define NUM_EDGES 50000
#define NUM_CONN  800000
#define IN_DIM    256
#define HIDDEN    128
#define EDGE_DIM  17
#define PAD       64

typedef __bf16 bf16x8 __attribute__((ext_vector_type(8)));
typedef float  f32x4  __attribute__((ext_vector_type(4)));

// ---------------- ws layout ----------------
// P     : bf16 [NUM_NODES][HIDDEN]   25,600,000 B @ 0
// counts: int  [NUM_EDGES]              200,000 B @ 25,600,000
// slots : int  [NUM_EDGES][PAD]      12,800,000 B @ 25,800,000
// W1F   : bf16 frag-major [8][8][64][8]  65,536 B @ 38,600,000
// W2F   : bf16 frag-major [4][2][64][8]   8,192 B @ 38,665,536

// Zero counts + pack W1/W2 into MFMA B-fragment-major bf16 (one launch).
__global__ void prep_kernel(const float* __restrict__ W1, const float* __restrict__ W2,
                            __bf16* __restrict__ w1f, __bf16* __restrict__ w2f,
                            int* __restrict__ counts) {
    int i = blockIdx.x * 256 + threadIdx.x;   // grid 196*256 = 50176
    if (i < NUM_EDGES) counts[i] = 0;
    if (i < 4096) {            // W1F[kc2][t][lane][ki]
        int lane = i & 63, t = (i >> 6) & 7, kc2 = i >> 9;
        int m = lane & 15, q = lane >> 4;
        int n = t * 16 + m;
        int kbase = kc2 * 32 + q * 8;
        __bf16* dst = w1f + (size_t)i * 8;
        #pragma unroll
        for (int ki = 0; ki < 8; ++ki)
            dst[ki] = (__bf16)W1[(size_t)(kbase + ki) * HIDDEN + n];
    } else if (i < 4608) {     // W2F[ks][t][lane][ki], n>=17 zero-padded
        int f = i - 4096;
        int lane = f & 63, t = (f >> 6) & 1, ks = f >> 7;
        int m = lane & 15, q = lane >> 4;
        int n = t * 16 + m;
        int kbase = ks * 32 + q * 8;
        __bf16* dst = w2f + (size_t)f * 8;
        #pragma unroll
        for (int ki = 0; ki < 8; ++ki)
            dst[ki] = (n < EDGE_DIM) ? (__bf16)W2[(size_t)(kbase + ki) * EDGE_DIM + n]
                                     : (__bf16)0.0f;
    }
}

// Fused bucket + proj.
// blockIdx % 3 == 1 -> bucket role (391 blocks, 8 conns/thread)
// else              -> proj role  (782 blocks; 128 rows x 128 cols, B in 64KB LDS,
//                                  A prefetched a full m-tile deep: vmcnt pipe carries
//                                  ONLY the A stream; B comes via lgkmcnt from LDS)
#define FRONT_BLOCKS 1173
__global__ __launch_bounds__(256) void front_kernel(const int* __restrict__ idx,
        int stride, int* __restrict__ counts, int* __restrict__ slots,
        const float* __restrict__ nf, const __bf16* __restrict__ w1f,
        __bf16* __restrict__ pbf) {
    __shared__ __align__(16) __bf16 lds_w[32768];   // 64 KB: all 8 n-tiles of W1F
    const int d3 = blockIdx.x / 3, r3 = blockIdx.x % 3;
    if (r3 == 1) {
        // ---- bucket role ----
        long c0 = ((long)d3 * 256 + threadIdx.x) * 8;
        if (c0 < NUM_CONN) {
            int nd[8], ed[8];
            if (stride == 2) {   // int64: int4 = 2 elems (lo words .x/.z)
                #pragma unroll
                for (int k = 0; k < 4; ++k) {
                    int4 vn = ((const int4*)idx)[c0 / 2 + k];
                    int4 ve = ((const int4*)(idx + 2 * NUM_CONN))[c0 / 2 + k];
                    nd[2 * k] = vn.x; nd[2 * k + 1] = vn.z;
                    ed[2 * k] = ve.x; ed[2 * k + 1] = ve.z;
                }
            } else {
                #pragma unroll
                for (int k = 0; k < 8; ++k) {
                    nd[k] = idx[c0 + k];
                    ed[k] = idx[NUM_CONN + c0 + k];
                }
            }
            int pos[8];
            #pragma unroll
            for (int k = 0; k < 8; ++k) pos[k] = atomicAdd(&counts[ed[k]], 1);
            #pragma unroll
            for (int k = 0; k < 8; ++k)
                if (pos[k] < PAD) slots[(size_t)ed[k] * PAD + pos[k]] = nd[k];
        }
        return;
    }
    // ---- proj role ----
    const int p = 2 * d3 + (r3 == 2 ? 1 : 0);    // 0..781
    {
        const uint4* src = (const uint4*)w1f;
        uint4* dst = (uint4*)lds_w;
        #pragma unroll
        for (int i = threadIdx.x; i < 4096; i += 256) dst[i] = src[i];
    }
    __syncthreads();

    const int wave = threadIdx.x >> 6;
    const int lane = threadIdx.x & 63;
    const int m = lane & 15, q = lane >> 4;
    const int rowbase = p * 128 + wave * 32;
    const bf16x8* frag = (const bf16x8*)lds_w;

    const float* ap[2];
    #pragma unroll
    for (int mt = 0; mt < 2; ++mt) {
        int r = rowbase + mt * 16 + m;
        if (r >= NUM_NODES) r = NUM_NODES - 1;
        ap[mt] = nf + (size_t)r * IN_DIM + q * 8;
    }

    f32x4 acc[2][8];
    #pragma unroll
    for (int mt = 0; mt < 2; ++mt)
        #pragma unroll
        for (int t = 0; t < 8; ++t) acc[mt][t] = (f32x4){0.f, 0.f, 0.f, 0.f};

    // Prefetch the ENTIRE first m-tile's A (16 float4 in flight per lane).
    float4 a4[16];
    #pragma unroll
    for (int kc2 = 0; kc2 < 8; ++kc2) {
        a4[2 * kc2]     = *(const float4*)(ap[0] + kc2 * 32);
        a4[2 * kc2 + 1] = *(const float4*)(ap[0] + kc2 * 32 + 4);
    }

    #pragma unroll
    for (int mt = 0; mt < 2; ++mt) {
        // convert current tile's A to bf16 fragments (waits on vmcnt here only)
        bf16x8 afr[8];
        #pragma unroll
        for (int kc2 = 0; kc2 < 8; ++kc2) {
            float4 f0 = a4[2 * kc2], f1 = a4[2 * kc2 + 1];
            afr[kc2][0] = (__bf16)f0.x; afr[kc2][1] = (__bf16)f0.y;
            afr[kc2][2] = (__bf16)f0.z; afr[kc2][3] = (__bf16)f0.w;
            afr[kc2][4] = (__bf16)f1.x; afr[kc2][5] = (__bf16)f1.y;
            afr[kc2][6] = (__bf16)f1.z; afr[kc2][7] = (__bf16)f1.w;
        }
        // issue next tile's A loads before the MFMA burst
        if (mt == 0) {
            #pragma unroll
            for (int kc2 = 0; kc2 < 8; ++kc2) {
                a4[2 * kc2]     = *(const float4*)(ap[1] + kc2 * 32);
                a4[2 * kc2 + 1] = *(const float4*)(ap[1] + kc2 * 32 + 4);
            }
        }
        // 64 MFMAs fed exclusively from LDS (lgkmcnt pipe)
        #pragma unroll
        for (int kc2 = 0; kc2 < 8; ++kc2) {
            #pragma unroll
            for (int t = 0; t < 8; ++t)
                acc[mt][t] = __builtin_amdgcn_mfma_f32_16x16x32_bf16(
                    afr[kc2], frag[(kc2 * 8 + t) * 64 + lane], acc[mt][t], 0, 0, 0);
        }
    }

    #pragma unroll
    for (int mt = 0; mt < 2; ++mt) {
        int ob = rowbase + mt * 16 + q * 4;
        #pragma unroll
        for (int t = 0; t < 8; ++t)
            #pragma unroll
            for (int r = 0; r < 4; ++r) {
                int orow = ob + r;
                if (orow < NUM_NODES)
                    pbf[(size_t)orow * HIDDEN + t * 16 + m] = (__bf16)acc[mt][t][r];
            }
    }
}

// 4 edges/wave, 16 lanes/edge gather + LN + ReLU, then the block's 16 edges
// (= one MFMA tile) go through LDS and wave 0 computes out = r@W2 + b2.
__global__ __launch_bounds__(256) void edge_kernel(const uint4* __restrict__ p4,
        const int* __restrict__ counts, const int* __restrict__ slots,
        const float* __restrict__ b1, const float* __restrict__ ln_g,
        const float* __restrict__ ln_b, const __bf16* __restrict__ w2f,
        const float* __restrict__ b2, float* __restrict__ out) {
    __shared__ __align__(16) uint4 lds_r[256];   // 16 edges x 128 bf16 = 4 KB
    const int wave = threadIdx.x >> 6;
    const int lane = threadIdx.x & 63;
    const int g = lane & 15, ge = lane >> 4;
    const int el = wave * 4 + ge;                 // edge-local 0..15
    const int e = blockIdx.x * 16 + el;

    const int c = counts[e];
    const int cc = c < PAD ? c : PAD;
    const float inv = 1.0f / (float)(c > 0 ? c : 1);

    float acc[8];
    #pragma unroll
    for (int d = 0; d < 8; ++d) acc[d] = 0.f;

    for (int c0 = 0; c0 < cc; c0 += 16) {
        int slv = slots[(size_t)e * PAD + c0 + g];
        int lim = cc - c0; if (lim > 16) lim = 16;
        if (lim == 16) {
            #pragma unroll
            for (int k0 = 0; k0 < 16; k0 += 4) {
                uint4 u[4];
                #pragma unroll
                for (int k = 0; k < 4; ++k) {
                    int nd = __shfl(slv, ge * 16 + k0 + k, 64);
                    u[k] = p4[(size_t)nd * 16 + g];
                }
                #pragma unroll
                for (int k = 0; k < 4; ++k) {
                    acc[0] += __uint_as_float(u[k].x << 16);
                    acc[1] += __uint_as_float(u[k].x & 0xffff0000u);
                    acc[2] += __uint_as_float(u[k].y << 16);
                    acc[3] += __uint_as_float(u[k].y & 0xffff0000u);
                    acc[4] += __uint_as_float(u[k].z << 16);
                    acc[5] += __uint_as_float(u[k].z & 0xffff0000u);
                    acc[6] += __uint_as_float(u[k].w << 16);
                    acc[7] += __uint_as_float(u[k].w & 0xffff0000u);
                }
            }
        } else {
            for (int k0 = 0; k0 < lim; k0 += 4) {
                uint4 u[4];
                unsigned okm[4];
                #pragma unroll
                for (int k = 0; k < 4; ++k) {
                    int nd = __shfl(slv, ge * 16 + k0 + k, 64);
                    nd = ((unsigned)nd < NUM_NODES) ? nd : 0;
                    u[k] = p4[(size_t)nd * 16 + g];
                    okm[k] = (k0 + k < lim) ? 0xffffffffu : 0u;
                }
                #pragma unroll
                for (int k = 0; k < 4; ++k) {
                    uint4 v = u[k];
                    v.x &= okm[k]; v.y &= okm[k]; v.z &= okm[k]; v.w &= okm[k];
                    acc[0] += __uint_as_float(v.x << 16);
                    acc[1] += __uint_as_float(v.x & 0xffff0000u);
                    acc[2] += __uint_as_float(v.y << 16);
                    acc[3] += __uint_as_float(v.y & 0xffff0000u);
                    acc[4] += __uint_as_float(v.z << 16);
                    acc[5] += __uint_as_float(v.z & 0xffff0000u);
                    acc[6] += __uint_as_float(v.w << 16);
                    acc[7] += __uint_as_float(v.w & 0xffff0000u);
                }
            }
        }
    }

    float4 bA = ((const float4*)b1)[2 * g];
    float4 bB = ((const float4*)b1)[2 * g + 1];
    float h[8];
    h[0] = acc[0] * inv + bA.x; h[1] = acc[1] * inv + bA.y;
    h[2] = acc[2] * inv + bA.z; h[3] = acc[3] * inv + bA.w;
    h[4] = acc[4] * inv + bB.x; h[5] = acc[5] * inv + bB.y;
    h[6] = acc[6] * inv + bB.z; h[7] = acc[7] * inv + bB.w;

    float s = 0.f;
    #pragma unroll
    for (int d = 0; d < 8; ++d) s += h[d];
    #pragma unroll
    for (int off = 8; off > 0; off >>= 1) s += __shfl_xor(s, off, 64);
    float mu = s * (1.0f / 128.0f);

    float dv[8], vv = 0.f;
    #pragma unroll
    for (int d = 0; d < 8; ++d) { dv[d] = h[d] - mu; vv += dv[d] * dv[d]; }
    #pragma unroll
    for (int off = 8; off > 0; off >>= 1) vv += __shfl_xor(vv, off, 64);
    float rs = rsqrtf(vv * (1.0f / 128.0f) + 1e-5f);

    float4 gA = ((const float4*)ln_g)[2 * g];
    float4 gB = ((const float4*)ln_g)[2 * g + 1];
    float4 eA = ((const float4*)ln_b)[2 * g];
    float4 eB = ((const float4*)ln_b)[2 * g + 1];
    float gg[8] = {gA.x, gA.y, gA.z, gA.w, gB.x, gB.y, gB.z, gB.w};
    float ee[8] = {eA.x, eA.y, eA.z, eA.w, eB.x, eB.y, eB.z, eB.w};
    union { __bf16 b[8]; uint4 u; } pk;
    #pragma unroll
    for (int d = 0; d < 8; ++d) {
        float r = dv[d] * rs * gg[d] + ee[d];
        pk.b[d] = (__bf16)(r > 0.f ? r : 0.f);
    }
    lds_r[el * 16 + g] = pk.u;
    __syncthreads();

    if (wave == 0) {   // out tile: [16 edges x 128] @ [128 x 32pad]
        const int m = lane & 15, q = lane >> 4;
        const __bf16* lr = (const __bf16*)lds_r;
        const bf16x8* fw = (const bf16x8*)w2f;
        f32x4 a0 = (f32x4){0.f, 0.f, 0.f, 0.f};
        f32x4 a1 = (f32x4){0.f, 0.f, 0.f, 0.f};
        #pragma unroll
        for (int ks = 0; ks < 4; ++ks) {
            bf16x8 a = *(const bf16x8*)(lr + m * 128 + ks * 32 + q * 8);
            a0 = __builtin_amdgcn_mfma_f32_16x16x32_bf16(a, fw[(ks * 2 + 0) * 64 + lane], a0, 0, 0, 0);
            a1 = __builtin_amdgcn_mfma_f32_16x16x32_bf16(a, fw[(ks * 2 + 1) * 64 + lane], a1, 0, 0, 0);
        }
        int rowb = blockIdx.x * 16 + q * 4;
        float bm = b2[m];
        float b16 = b2[16];
        #pragma unroll
        for (int r = 0; r < 4; ++r) {
            out[(size_t)(rowb + r) * EDGE_DIM + m] = a0[r] + bm;
            if (m == 0) out[(size_t)(rowb + r) * EDGE_DIM + 16] = a1[r] + b16;
        }
    }
}

extern "C" void kernel_launch(void* const* d_in, const int* in_sizes, int n_in,
                              void* d_out, int out_size, void* d_ws, size_t ws_size,
                              hipStream_t stream) {
    const float* nf  = (const float*)d_in[0];
    const int*   idx = (const int*)d_in[1];
    const float* W1  = (const float*)d_in[2];
    const float* b1  = (const float*)d_in[3];
    const float* g   = (const float*)d_in[4];
    const float* be  = (const float*)d_in[5];
    const float* W2  = (const float*)d_in[6];
    const float* b2  = (const float*)d_in[7];
    float* out = (float*)d_out;

    char* ws = (char*)d_ws;
    __bf16* P      = (__bf16*)ws;
    int*    counts = (int*)(ws + 25600000);
    int*    slots  = (int*)(ws + 25800000);
    __bf16* W1F    = (__bf16*)(ws + 38600000);
    __bf16* W2F    = (__bf16*)(ws + 38665536);

    int stride = (in_sizes[1] == 2 * NUM_CONN) ? 1 : 2;

    prep_kernel<<<196, 256, 0, stream>>>(W1, W2, W1F, W2F, counts);
    front_kernel<<<FRONT_BLOCKS, 256, 0, stream>>>(idx, stride, counts, slots, nf, W1F, P);
    edge_kernel<<<NUM_EDGES / 16, 256, 0, stream>>>((const uint4*)P, counts, slots,
                                                    b1, g, be, W2F, b2, out);
}

// Round 9
// 238.538 us; speedup vs baseline: 1.0960x; 1.0807x over previous
//
#include <hip/hip_runtime.h>
#include <hip/hip_bf16.h>
#include <stdint.h>

#define NUM_NODES 100000
#define NUM_EDGES 50000
#define NUM_CONN  800000
#define IN_DIM    256
#define HIDDEN    128
#define EDGE_DIM  17
#define PAD       64

typedef __bf16 bf16x8 __attribute__((ext_vector_type(8)));
typedef float  f32x4  __attribute__((ext_vector_type(4)));

// ---------------- ws layout ----------------
// P     : bf16 [NUM_NODES][HIDDEN]   25,600,000 B @ 0
// counts: int  [NUM_EDGES]              200,000 B @ 25,600,000
// slots : int  [NUM_EDGES][PAD]      12,800,000 B @ 25,800,000
// W1F   : bf16 frag-major [8][8][64][8]  65,536 B @ 38,600,000
// W2F   : bf16 frag-major [4][2][64][8]   8,192 B @ 38,665,536

// Zero counts + pack W1/W2 into MFMA B-fragment-major bf16 (one launch).
__global__ void prep_kernel(const float* __restrict__ W1, const float* __restrict__ W2,
                            __bf16* __restrict__ w1f, __bf16* __restrict__ w2f,
                            int* __restrict__ counts) {
    int i = blockIdx.x * 256 + threadIdx.x;   // grid 196*256 = 50176
    if (i < NUM_EDGES) counts[i] = 0;
    if (i < 4096) {            // W1F[kc2][t][lane][ki]
        int lane = i & 63, t = (i >> 6) & 7, kc2 = i >> 9;
        int m = lane & 15, q = lane >> 4;
        int n = t * 16 + m;
        int kbase = kc2 * 32 + q * 8;
        __bf16* dst = w1f + (size_t)i * 8;
        #pragma unroll
        for (int ki = 0; ki < 8; ++ki)
            dst[ki] = (__bf16)W1[(size_t)(kbase + ki) * HIDDEN + n];
    } else if (i < 4608) {     // W2F[ks][t][lane][ki], n>=17 zero-padded
        int f = i - 4096;
        int lane = f & 63, t = (f >> 6) & 1, ks = f >> 7;
        int m = lane & 15, q = lane >> 4;
        int n = t * 16 + m;
        int kbase = ks * 32 + q * 8;
        __bf16* dst = w2f + (size_t)f * 8;
        #pragma unroll
        for (int ki = 0; ki < 8; ++ki)
            dst[ki] = (n < EDGE_DIM) ? (__bf16)W2[(size_t)(kbase + ki) * EDGE_DIM + n]
                                     : (__bf16)0.0f;
    }
}

// Fused bucket + proj.
// blockIdx % 5 == 2 -> bucket role (391 blocks, 8 conns/thread).
// else              -> proj role (1564 blocks; 64 rows x 128 cols). A-tile loaded
//   ONCE into registers; B двух-phase через 32 KB LDS (cols 0-63 then 64-127),
//   so nf is read once, B feeds MFMA via lgkmcnt, and LDS stays at 32 KB for
//   4 blocks/CU occupancy (the R8 64 KB version collapsed to 9% occupancy).
#define FRONT_BLOCKS 1955
__global__ __launch_bounds__(256, 4) void front_kernel(const int* __restrict__ idx,
        int stride, int* __restrict__ counts, int* __restrict__ slots,
        const float* __restrict__ nf, const __bf16* __restrict__ w1f,
        __bf16* __restrict__ pbf) {
    __shared__ __align__(16) __bf16 lds_w[16384];   // 32 KB: 4 n-tiles per phase
    const int nb = blockIdx.x / 5, r5 = blockIdx.x % 5;
    if (r5 == 2) {
        // ---- bucket role: 8 independent atomic chains per thread ----
        long c0 = ((long)nb * 256 + threadIdx.x) * 8;
        if (c0 < NUM_CONN) {
            int nd[8], ed[8];
            if (stride == 2) {   // int64: int4 = 2 elems (lo words .x/.z)
                #pragma unroll
                for (int k = 0; k < 4; ++k) {
                    int4 vn = ((const int4*)idx)[c0 / 2 + k];
                    int4 ve = ((const int4*)(idx + 2 * NUM_CONN))[c0 / 2 + k];
                    nd[2 * k] = vn.x; nd[2 * k + 1] = vn.z;
                    ed[2 * k] = ve.x; ed[2 * k + 1] = ve.z;
                }
            } else {
                #pragma unroll
                for (int k = 0; k < 8; ++k) {
                    nd[k] = idx[c0 + k];
                    ed[k] = idx[NUM_CONN + c0 + k];
                }
            }
            int pos[8];
            #pragma unroll
            for (int k = 0; k < 8; ++k) pos[k] = atomicAdd(&counts[ed[k]], 1);
            #pragma unroll
            for (int k = 0; k < 8; ++k)
                if (pos[k] < PAD) slots[(size_t)ed[k] * PAD + pos[k]] = nd[k];
        }
        return;
    }
    // ---- proj role ----
    const int p = blockIdx.x - nb - (r5 > 2 ? 1 : 0);   // 0..1563
    const int wave = threadIdx.x >> 6;
    const int lane = threadIdx.x & 63;
    const int m = lane & 15, q = lane >> 4;
    int row = p * 64 + wave * 16 + m;
    if (row >= NUM_NODES) row = NUM_NODES - 1;          // clamp; stores guarded
    const float* ap = nf + (size_t)row * IN_DIM + q * 8;

    const uint4* src = (const uint4*)w1f;
    uint4* dst = (uint4*)lds_w;

    // A-tile: two 8-float4 batches (bounds VGPR pressure), convert to bf16 frags.
    bf16x8 afr[8];
    {
        float4 a4[8];
        #pragma unroll
        for (int kc2 = 0; kc2 < 4; ++kc2) {
            a4[2 * kc2]     = *(const float4*)(ap + kc2 * 32);
            a4[2 * kc2 + 1] = *(const float4*)(ap + kc2 * 32 + 4);
        }
        // stage phase-0 B half while A batch 0 is in flight
        #pragma unroll
        for (int i = threadIdx.x; i < 2048; i += 256) {
            int kc2 = i >> 8, tt = (i >> 6) & 3, l = i & 63;
            dst[i] = src[(kc2 * 8 + tt) * 64 + l];
        }
        #pragma unroll
        for (int kc2 = 0; kc2 < 4; ++kc2) {
            float4 f0 = a4[2 * kc2], f1 = a4[2 * kc2 + 1];
            afr[kc2][0] = (__bf16)f0.x; afr[kc2][1] = (__bf16)f0.y;
            afr[kc2][2] = (__bf16)f0.z; afr[kc2][3] = (__bf16)f0.w;
            afr[kc2][4] = (__bf16)f1.x; afr[kc2][5] = (__bf16)f1.y;
            afr[kc2][6] = (__bf16)f1.z; afr[kc2][7] = (__bf16)f1.w;
        }
        #pragma unroll
        for (int kc2 = 4; kc2 < 8; ++kc2) {
            a4[2 * (kc2 - 4)]     = *(const float4*)(ap + kc2 * 32);
            a4[2 * (kc2 - 4) + 1] = *(const float4*)(ap + kc2 * 32 + 4);
        }
        #pragma unroll
        for (int kc2 = 4; kc2 < 8; ++kc2) {
            float4 f0 = a4[2 * (kc2 - 4)], f1 = a4[2 * (kc2 - 4) + 1];
            afr[kc2][0] = (__bf16)f0.x; afr[kc2][1] = (__bf16)f0.y;
            afr[kc2][2] = (__bf16)f0.z; afr[kc2][3] = (__bf16)f0.w;
            afr[kc2][4] = (__bf16)f1.x; afr[kc2][5] = (__bf16)f1.y;
            afr[kc2][6] = (__bf16)f1.z; afr[kc2][7] = (__bf16)f1.w;
        }
    }
    __syncthreads();

    const bf16x8* frag = (const bf16x8*)lds_w;
    #pragma unroll
    for (int ph = 0; ph < 2; ++ph) {
        f32x4 acc[4];
        #pragma unroll
        for (int tt = 0; tt < 4; ++tt) acc[tt] = (f32x4){0.f, 0.f, 0.f, 0.f};
        #pragma unroll
        for (int kc2 = 0; kc2 < 8; ++kc2) {
            #pragma unroll
            for (int tt = 0; tt < 4; ++tt)
                acc[tt] = __builtin_amdgcn_mfma_f32_16x16x32_bf16(
                    afr[kc2], frag[(kc2 * 4 + tt) * 64 + lane], acc[tt], 0, 0, 0);
        }
        int ob = p * 64 + wave * 16 + q * 4;
        #pragma unroll
        for (int tt = 0; tt < 4; ++tt) {
            int col = (ph * 4 + tt) * 16 + m;
            #pragma unroll
            for (int r = 0; r < 4; ++r) {
                int orow = ob + r;
                if (orow < NUM_NODES)
                    pbf[(size_t)orow * HIDDEN + col] = (__bf16)acc[tt][r];
            }
        }
        if (ph == 0) {
            __syncthreads();   // phase-0 LDS reads complete before overwrite
            #pragma unroll
            for (int i = threadIdx.x; i < 2048; i += 256) {
                int kc2 = i >> 8, tt = (i >> 6) & 3, l = i & 63;
                dst[i] = src[(kc2 * 8 + 4 + tt) * 64 + l];
            }
            __syncthreads();
        }
    }
}

// 4 edges/wave, 16 lanes/edge gather + LN + ReLU, then the block's 16 edges
// (= one MFMA tile) go through LDS and wave 0 computes out = r@W2 + b2.
__global__ __launch_bounds__(256) void edge_kernel(const uint4* __restrict__ p4,
        const int* __restrict__ counts, const int* __restrict__ slots,
        const float* __restrict__ b1, const float* __restrict__ ln_g,
        const float* __restrict__ ln_b, const __bf16* __restrict__ w2f,
        const float* __restrict__ b2, float* __restrict__ out) {
    __shared__ __align__(16) uint4 lds_r[256];   // 16 edges x 128 bf16 = 4 KB
    const int wave = threadIdx.x >> 6;
    const int lane = threadIdx.x & 63;
    const int g = lane & 15, ge = lane >> 4;
    const int el = wave * 4 + ge;                 // edge-local 0..15
    const int e = blockIdx.x * 16 + el;

    const int c = counts[e];
    const int cc = c < PAD ? c : PAD;
    const float inv = 1.0f / (float)(c > 0 ? c : 1);

    float acc[8];
    #pragma unroll
    for (int d = 0; d < 8; ++d) acc[d] = 0.f;

    for (int c0 = 0; c0 < cc; c0 += 16) {
        int slv = slots[(size_t)e * PAD + c0 + g];
        int lim = cc - c0; if (lim > 16) lim = 16;
        if (lim == 16) {
            #pragma unroll
            for (int k0 = 0; k0 < 16; k0 += 4) {
                uint4 u[4];
                #pragma unroll
                for (int k = 0; k < 4; ++k) {
                    int nd = __shfl(slv, ge * 16 + k0 + k, 64);
                    u[k] = p4[(size_t)nd * 16 + g];
                }
                #pragma unroll
                for (int k = 0; k < 4; ++k) {
                    acc[0] += __uint_as_float(u[k].x << 16);
                    acc[1] += __uint_as_float(u[k].x & 0xffff0000u);
                    acc[2] += __uint_as_float(u[k].y << 16);
                    acc[3] += __uint_as_float(u[k].y & 0xffff0000u);
                    acc[4] += __uint_as_float(u[k].z << 16);
                    acc[5] += __uint_as_float(u[k].z & 0xffff0000u);
                    acc[6] += __uint_as_float(u[k].w << 16);
                    acc[7] += __uint_as_float(u[k].w & 0xffff0000u);
                }
            }
        } else {
            for (int k0 = 0; k0 < lim; k0 += 4) {
                uint4 u[4];
                unsigned okm[4];
                #pragma unroll
                for (int k = 0; k < 4; ++k) {
                    int nd = __shfl(slv, ge * 16 + k0 + k, 64);
                    nd = ((unsigned)nd < NUM_NODES) ? nd : 0;
                    u[k] = p4[(size_t)nd * 16 + g];
                    okm[k] = (k0 + k < lim) ? 0xffffffffu : 0u;
                }
                #pragma unroll
                for (int k = 0; k < 4; ++k) {
                    uint4 v = u[k];
                    v.x &= okm[k]; v.y &= okm[k]; v.z &= okm[k]; v.w &= okm[k];
                    acc[0] += __uint_as_float(v.x << 16);
                    acc[1] += __uint_as_float(v.x & 0xffff0000u);
                    acc[2] += __uint_as_float(v.y << 16);
                    acc[3] += __uint_as_float(v.y & 0xffff0000u);
                    acc[4] += __uint_as_float(v.z << 16);
                    acc[5] += __uint_as_float(v.z & 0xffff0000u);
                    acc[6] += __uint_as_float(v.w << 16);
                    acc[7] += __uint_as_float(v.w & 0xffff0000u);
                }
            }
        }
    }

    float4 bA = ((const float4*)b1)[2 * g];
    float4 bB = ((const float4*)b1)[2 * g + 1];
    float h[8];
    h[0] = acc[0] * inv + bA.x; h[1] = acc[1] * inv + bA.y;
    h[2] = acc[2] * inv + bA.z; h[3] = acc[3] * inv + bA.w;
    h[4] = acc[4] * inv + bB.x; h[5] = acc[5] * inv + bB.y;
    h[6] = acc[6] * inv + bB.z; h[7] = acc[7] * inv + bB.w;

    float s = 0.f;
    #pragma unroll
    for (int d = 0; d < 8; ++d) s += h[d];
    #pragma unroll
    for (int off = 8; off > 0; off >>= 1) s += __shfl_xor(s, off, 64);
    float mu = s * (1.0f / 128.0f);

    float dv[8], vv = 0.f;
    #pragma unroll
    for (int d = 0; d < 8; ++d) { dv[d] = h[d] - mu; vv += dv[d] * dv[d]; }
    #pragma unroll
    for (int off = 8; off > 0; off >>= 1) vv += __shfl_xor(vv, off, 64);
    float rs = rsqrtf(vv * (1.0f / 128.0f) + 1e-5f);

    float4 gA = ((const float4*)ln_g)[2 * g];
    float4 gB = ((const float4*)ln_g)[2 * g + 1];
    float4 eA = ((const float4*)ln_b)[2 * g];
    float4 eB = ((const float4*)ln_b)[2 * g + 1];
    float gg[8] = {gA.x, gA.y, gA.z, gA.w, gB.x, gB.y, gB.z, gB.w};
    float ee[8] = {eA.x, eA.y, eA.z, eA.w, eB.x, eB.y, eB.z, eB.w};
    union { __bf16 b[8]; uint4 u; } pk;
    #pragma unroll
    for (int d = 0; d < 8; ++d) {
        float r = dv[d] * rs * gg[d] + ee[d];
        pk.b[d] = (__bf16)(r > 0.f ? r : 0.f);
    }
    lds_r[el * 16 + g] = pk.u;
    __syncthreads();

    if (wave == 0) {   // out tile: [16 edges x 128] @ [128 x 32pad]
        const int m = lane & 15, q = lane >> 4;
        const __bf16* lr = (const __bf16*)lds_r;
        const bf16x8* fw = (const bf16x8*)w2f;
        f32x4 a0 = (f32x4){0.f, 0.f, 0.f, 0.f};
        f32x4 a1 = (f32x4){0.f, 0.f, 0.f, 0.f};
        #pragma unroll
        for (int ks = 0; ks < 4; ++ks) {
            bf16x8 a = *(const bf16x8*)(lr + m * 128 + ks * 32 + q * 8);
            a0 = __builtin_amdgcn_mfma_f32_16x16x32_bf16(a, fw[(ks * 2 + 0) * 64 + lane], a0, 0, 0, 0);
            a1 = __builtin_amdgcn_mfma_f32_16x16x32_bf16(a, fw[(ks * 2 + 1) * 64 + lane], a1, 0, 0, 0);
        }
        int rowb = blockIdx.x * 16 + q * 4;
        float bm = b2[m];
        float b16 = b2[16];
        #pragma unroll
        for (int r = 0; r < 4; ++r) {
            out[(size_t)(rowb + r) * EDGE_DIM + m] = a0[r] + bm;
            if (m == 0) out[(size_t)(rowb + r) * EDGE_DIM + 16] = a1[r] + b16;
        }
    }
}

extern "C" void kernel_launch(void* const* d_in, const int* in_sizes, int n_in,
                              void* d_out, int out_size, void* d_ws, size_t ws_size,
                              hipStream_t stream) {
    const float* nf  = (const float*)d_in[0];
    const int*   idx = (const int*)d_in[1];
    const float* W1  = (const float*)d_in[2];
    const float* b1  = (const float*)d_in[3];
    const float* g   = (const float*)d_in[4];
    const float* be  = (const float*)d_in[5];
    const float* W2  = (const float*)d_in[6];
    const float* b2  = (const float*)d_in[7];
    float* out = (float*)d_out;

    char* ws = (char*)d_ws;
    __bf16* P      = (__bf16*)ws;
    int*    counts = (int*)(ws + 25600000);
    int*    slots  = (int*)(ws + 25800000);
    __bf16* W1F    = (__bf16*)(ws + 38600000);
    __bf16* W2F    = (__bf16*)(ws + 38665536);

    int stride = (in_sizes[1] == 2 * NUM_CONN) ? 1 : 2;

    prep_kernel<<<196, 256, 0, stream>>>(W1, W2, W1F, W2F, counts);
    front_kernel<<<FRONT_BLOCKS, 256, 0, stream>>>(idx, stride, counts, slots, nf, W1F, P);
    edge_kernel<<<NUM_EDGES / 16, 256, 0, stream>>>((const uint4*)P, counts, slots,
                                                    b1, g, be, W2F, b2, out);
}

// Round 10
// 234.815 us; speedup vs baseline: 1.1134x; 1.0159x over previous
//
#include <hip/hip_runtime.h>
#include <hip/hip_bf16.h>
#include <stdint.h>

#define NUM_NODES 100000
#define NUM_EDGES 50000
#define NUM_CONN  800000
#define IN_DIM    256
#define HIDDEN    128
#define EDGE_DIM  17
#define PAD       64
#define CSTRIDE   16   /* counts padded to one 64B line per edge: kills same-line atomic serialization */

typedef __bf16 bf16x8 __attribute__((ext_vector_type(8)));
typedef float  f32x4  __attribute__((ext_vector_type(4)));

// ---------------- ws layout ----------------
// P      : bf16 [NUM_NODES][HIDDEN]    25,600,000 B @ 0
// counts2: int  [NUM_EDGES*16]          3,200,000 B @ 25,600,000
// slots  : int  [NUM_EDGES][PAD]       12,800,000 B @ 28,800,000
// W1F    : bf16 frag-major [8][8][64][8]   65,536 B @ 41,600,000
// W2F    : bf16 frag-major [4][2][64][8]    8,192 B @ 41,665,536

// Zero padded counts + pack W1/W2 into MFMA B-fragment-major bf16.
__global__ void prep_kernel(const float* __restrict__ W1, const float* __restrict__ W2,
                            __bf16* __restrict__ w1f, __bf16* __restrict__ w2f,
                            int* __restrict__ counts2) {
    int i = blockIdx.x * 256 + threadIdx.x;   // grid 196*256 = 50176
    if (i < NUM_EDGES) {
        int4 z = {0, 0, 0, 0};
        int4* c4 = (int4*)(counts2 + (size_t)i * CSTRIDE);
        c4[0] = z; c4[1] = z; c4[2] = z; c4[3] = z;
    }
    if (i < 4096) {            // W1F[kc2][t][lane][ki]
        int lane = i & 63, t = (i >> 6) & 7, kc2 = i >> 9;
        int m = lane & 15, q = lane >> 4;
        int n = t * 16 + m;
        int kbase = kc2 * 32 + q * 8;
        __bf16* dst = w1f + (size_t)i * 8;
        #pragma unroll
        for (int ki = 0; ki < 8; ++ki)
            dst[ki] = (__bf16)W1[(size_t)(kbase + ki) * HIDDEN + n];
    } else if (i < 4608) {     // W2F[ks][t][lane][ki], n>=17 zero-padded
        int f = i - 4096;
        int lane = f & 63, t = (f >> 6) & 1, ks = f >> 7;
        int m = lane & 15, q = lane >> 4;
        int n = t * 16 + m;
        int kbase = ks * 32 + q * 8;
        __bf16* dst = w2f + (size_t)f * 8;
        #pragma unroll
        for (int ki = 0; ki < 8; ++ki)
            dst[ki] = (n < EDGE_DIM) ? (__bf16)W2[(size_t)(kbase + ki) * EDGE_DIM + n]
                                     : (__bf16)0.0f;
    }
}

// Fused bucket + proj.
// blockIdx % 3 == 1 -> bucket role (782 blocks, 4 conns/thread, line-padded counters)
// else              -> proj role (1564 blocks; 64 rows x 128 cols, two-phase 32KB LDS)
#define FRONT_BLOCKS 2346
__global__ __launch_bounds__(256, 4) void front_kernel(const int* __restrict__ idx,
        int stride, int* __restrict__ counts2, int* __restrict__ slots,
        const float* __restrict__ nf, const __bf16* __restrict__ w1f,
        __bf16* __restrict__ pbf) {
    __shared__ __align__(16) __bf16 lds_w[16384];   // 32 KB: 4 n-tiles per phase
    const int nb = blockIdx.x / 3, r3 = blockIdx.x % 3;
    if (r3 == 1) {
        // ---- bucket role: 4 conns/thread, padded counters ----
        long c0 = ((long)nb * 256 + threadIdx.x) * 4;
        if (c0 < NUM_CONN) {
            int nd[4], ed[4];
            if (stride == 2) {   // int64: int4 = 2 elems (lo words .x/.z)
                #pragma unroll
                for (int k = 0; k < 2; ++k) {
                    int4 vn = ((const int4*)idx)[c0 / 2 + k];
                    int4 ve = ((const int4*)(idx + 2 * NUM_CONN))[c0 / 2 + k];
                    nd[2 * k] = vn.x; nd[2 * k + 1] = vn.z;
                    ed[2 * k] = ve.x; ed[2 * k + 1] = ve.z;
                }
            } else {
                #pragma unroll
                for (int k = 0; k < 4; ++k) {
                    nd[k] = idx[c0 + k];
                    ed[k] = idx[NUM_CONN + c0 + k];
                }
            }
            int pos[4];
            #pragma unroll
            for (int k = 0; k < 4; ++k)
                pos[k] = atomicAdd(&counts2[(size_t)ed[k] * CSTRIDE], 1);
            #pragma unroll
            for (int k = 0; k < 4; ++k)
                if (pos[k] < PAD) slots[(size_t)ed[k] * PAD + pos[k]] = nd[k];
        }
        return;
    }
    // ---- proj role ----
    const int p = 2 * nb + (r3 == 2 ? 1 : 0);   // 0..1563
    const int wave = threadIdx.x >> 6;
    const int lane = threadIdx.x & 63;
    const int m = lane & 15, q = lane >> 4;
    int row = p * 64 + wave * 16 + m;
    if (row >= NUM_NODES) row = NUM_NODES - 1;          // clamp; stores guarded
    const float* ap = nf + (size_t)row * IN_DIM + q * 8;

    const uint4* src = (const uint4*)w1f;
    uint4* dst = (uint4*)lds_w;

    // A-tile: two 8-float4 batches (bounds VGPR pressure), convert to bf16 frags.
    bf16x8 afr[8];
    {
        float4 a4[8];
        #pragma unroll
        for (int kc2 = 0; kc2 < 4; ++kc2) {
            a4[2 * kc2]     = *(const float4*)(ap + kc2 * 32);
            a4[2 * kc2 + 1] = *(const float4*)(ap + kc2 * 32 + 4);
        }
        // stage phase-0 B half while A batch 0 is in flight
        #pragma unroll
        for (int i = threadIdx.x; i < 2048; i += 256) {
            int kc2 = i >> 8, tt = (i >> 6) & 3, l = i & 63;
            dst[i] = src[(kc2 * 8 + tt) * 64 + l];
        }
        #pragma unroll
        for (int kc2 = 0; kc2 < 4; ++kc2) {
            float4 f0 = a4[2 * kc2], f1 = a4[2 * kc2 + 1];
            afr[kc2][0] = (__bf16)f0.x; afr[kc2][1] = (__bf16)f0.y;
            afr[kc2][2] = (__bf16)f0.z; afr[kc2][3] = (__bf16)f0.w;
            afr[kc2][4] = (__bf16)f1.x; afr[kc2][5] = (__bf16)f1.y;
            afr[kc2][6] = (__bf16)f1.z; afr[kc2][7] = (__bf16)f1.w;
        }
        #pragma unroll
        for (int kc2 = 4; kc2 < 8; ++kc2) {
            a4[2 * (kc2 - 4)]     = *(const float4*)(ap + kc2 * 32);
            a4[2 * (kc2 - 4) + 1] = *(const float4*)(ap + kc2 * 32 + 4);
        }
        #pragma unroll
        for (int kc2 = 4; kc2 < 8; ++kc2) {
            float4 f0 = a4[2 * (kc2 - 4)], f1 = a4[2 * (kc2 - 4) + 1];
            afr[kc2][0] = (__bf16)f0.x; afr[kc2][1] = (__bf16)f0.y;
            afr[kc2][2] = (__bf16)f0.z; afr[kc2][3] = (__bf16)f0.w;
            afr[kc2][4] = (__bf16)f1.x; afr[kc2][5] = (__bf16)f1.y;
            afr[kc2][6] = (__bf16)f1.z; afr[kc2][7] = (__bf16)f1.w;
        }
    }
    __syncthreads();

    const bf16x8* frag = (const bf16x8*)lds_w;
    #pragma unroll
    for (int ph = 0; ph < 2; ++ph) {
        f32x4 acc[4];
        #pragma unroll
        for (int tt = 0; tt < 4; ++tt) acc[tt] = (f32x4){0.f, 0.f, 0.f, 0.f};
        #pragma unroll
        for (int kc2 = 0; kc2 < 8; ++kc2) {
            #pragma unroll
            for (int tt = 0; tt < 4; ++tt)
                acc[tt] = __builtin_amdgcn_mfma_f32_16x16x32_bf16(
                    afr[kc2], frag[(kc2 * 4 + tt) * 64 + lane], acc[tt], 0, 0, 0);
        }
        int ob = p * 64 + wave * 16 + q * 4;
        #pragma unroll
        for (int tt = 0; tt < 4; ++tt) {
            int col = (ph * 4 + tt) * 16 + m;
            #pragma unroll
            for (int r = 0; r < 4; ++r) {
                int orow = ob + r;
                if (orow < NUM_NODES)
                    pbf[(size_t)orow * HIDDEN + col] = (__bf16)acc[tt][r];
            }
        }
        if (ph == 0) {
            __syncthreads();   // phase-0 LDS reads complete before overwrite
            #pragma unroll
            for (int i = threadIdx.x; i < 2048; i += 256) {
                int kc2 = i >> 8, tt = (i >> 6) & 3, l = i & 63;
                dst[i] = src[(kc2 * 8 + 4 + tt) * 64 + l];
            }
            __syncthreads();
        }
    }
}

// 4 edges/wave, 16 lanes/edge gather + LN + ReLU, then the block's 16 edges
// (= one MFMA tile) go through LDS and wave 0 computes out = r@W2 + b2.
__global__ __launch_bounds__(256) void edge_kernel(const uint4* __restrict__ p4,
        const int* __restrict__ counts2, const int* __restrict__ slots,
        const float* __restrict__ b1, const float* __restrict__ ln_g,
        const float* __restrict__ ln_b, const __bf16* __restrict__ w2f,
        const float* __restrict__ b2, float* __restrict__ out) {
    __shared__ __align__(16) uint4 lds_r[256];   // 16 edges x 128 bf16 = 4 KB
    const int wave = threadIdx.x >> 6;
    const int lane = threadIdx.x & 63;
    const int g = lane & 15, ge = lane >> 4;
    const int el = wave * 4 + ge;                 // edge-local 0..15
    const int e = blockIdx.x * 16 + el;

    const int c = counts2[(size_t)e * CSTRIDE];
    const int cc = c < PAD ? c : PAD;
    const float inv = 1.0f / (float)(c > 0 ? c : 1);

    float acc[8];
    #pragma unroll
    for (int d = 0; d < 8; ++d) acc[d] = 0.f;

    for (int c0 = 0; c0 < cc; c0 += 16) {
        int slv = slots[(size_t)e * PAD + c0 + g];
        int lim = cc - c0; if (lim > 16) lim = 16;
        if (lim == 16) {
            #pragma unroll
            for (int k0 = 0; k0 < 16; k0 += 4) {
                uint4 u[4];
                #pragma unroll
                for (int k = 0; k < 4; ++k) {
                    int nd = __shfl(slv, ge * 16 + k0 + k, 64);
                    u[k] = p4[(size_t)nd * 16 + g];
                }
                #pragma unroll
                for (int k = 0; k < 4; ++k) {
                    acc[0] += __uint_as_float(u[k].x << 16);
                    acc[1] += __uint_as_float(u[k].x & 0xffff0000u);
                    acc[2] += __uint_as_float(u[k].y << 16);
                    acc[3] += __uint_as_float(u[k].y & 0xffff0000u);
                    acc[4] += __uint_as_float(u[k].z << 16);
                    acc[5] += __uint_as_float(u[k].z & 0xffff0000u);
                    acc[6] += __uint_as_float(u[k].w << 16);
                    acc[7] += __uint_as_float(u[k].w & 0xffff0000u);
                }
            }
        } else {
            for (int k0 = 0; k0 < lim; k0 += 4) {
                uint4 u[4];
                unsigned okm[4];
                #pragma unroll
                for (int k = 0; k < 4; ++k) {
                    int nd = __shfl(slv, ge * 16 + k0 + k, 64);
                    nd = ((unsigned)nd < NUM_NODES) ? nd : 0;
                    u[k] = p4[(size_t)nd * 16 + g];
                    okm[k] = (k0 + k < lim) ? 0xffffffffu : 0u;
                }
                #pragma unroll
                for (int k = 0; k < 4; ++k) {
                    uint4 v = u[k];
                    v.x &= okm[k]; v.y &= okm[k]; v.z &= okm[k]; v.w &= okm[k];
                    acc[0] += __uint_as_float(v.x << 16);
                    acc[1] += __uint_as_float(v.x & 0xffff0000u);
                    acc[2] += __uint_as_float(v.y << 16);
                    acc[3] += __uint_as_float(v.y & 0xffff0000u);
                    acc[4] += __uint_as_float(v.z << 16);
                    acc[5] += __uint_as_float(v.z & 0xffff0000u);
                    acc[6] += __uint_as_float(v.w << 16);
                    acc[7] += __uint_as_float(v.w & 0xffff0000u);
                }
            }
        }
    }

    float4 bA = ((const float4*)b1)[2 * g];
    float4 bB = ((const float4*)b1)[2 * g + 1];
    float h[8];
    h[0] = acc[0] * inv + bA.x; h[1] = acc[1] * inv + bA.y;
    h[2] = acc[2] * inv + bA.z; h[3] = acc[3] * inv + bA.w;
    h[4] = acc[4] * inv + bB.x; h[5] = acc[5] * inv + bB.y;
    h[6] = acc[6] * inv + bB.z; h[7] = acc[7] * inv + bB.w;

    float s = 0.f;
    #pragma unroll
    for (int d = 0; d < 8; ++d) s += h[d];
    #pragma unroll
    for (int off = 8; off > 0; off >>= 1) s += __shfl_xor(s, off, 64);
    float mu = s * (1.0f / 128.0f);

    float dv[8], vv = 0.f;
    #pragma unroll
    for (int d = 0; d < 8; ++d) { dv[d] = h[d] - mu; vv += dv[d] * dv[d]; }
    #pragma unroll
    for (int off = 8; off > 0; off >>= 1) vv += __shfl_xor(vv, off, 64);
    float rs = rsqrtf(vv * (1.0f / 128.0f) + 1e-5f);

    float4 gA = ((const float4*)ln_g)[2 * g];
    float4 gB = ((const float4*)ln_g)[2 * g + 1];
    float4 eA = ((const float4*)ln_b)[2 * g];
    float4 eB = ((const float4*)ln_b)[2 * g + 1];
    float gg[8] = {gA.x, gA.y, gA.z, gA.w, gB.x, gB.y, gB.z, gB.w};
    float ee[8] = {eA.x, eA.y, eA.z, eA.w, eB.x, eB.y, eB.z, eB.w};
    union { __bf16 b[8]; uint4 u; } pk;
    #pragma unroll
    for (int d = 0; d < 8; ++d) {
        float r = dv[d] * rs * gg[d] + ee[d];
        pk.b[d] = (__bf16)(r > 0.f ? r : 0.f);
    }
    lds_r[el * 16 + g] = pk.u;
    __syncthreads();

    if (wave == 0) {   // out tile: [16 edges x 128] @ [128 x 32pad]
        const int m = lane & 15, q = lane >> 4;
        const __bf16* lr = (const __bf16*)lds_r;
        const bf16x8* fw = (const bf16x8*)w2f;
        f32x4 a0 = (f32x4){0.f, 0.f, 0.f, 0.f};
        f32x4 a1 = (f32x4){0.f, 0.f, 0.f, 0.f};
        #pragma unroll
        for (int ks = 0; ks < 4; ++ks) {
            bf16x8 a = *(const bf16x8*)(lr + m * 128 + ks * 32 + q * 8);
            a0 = __builtin_amdgcn_mfma_f32_16x16x32_bf16(a, fw[(ks * 2 + 0) * 64 + lane], a0, 0, 0, 0);
            a1 = __builtin_amdgcn_mfma_f32_16x16x32_bf16(a, fw[(ks * 2 + 1) * 64 + lane], a1, 0, 0, 0);
        }
        int rowb = blockIdx.x * 16 + q * 4;
        float bm = b2[m];
        float b16 = b2[16];
        #pragma unroll
        for (int r = 0; r < 4; ++r) {
            out[(size_t)(rowb + r) * EDGE_DIM + m] = a0[r] + bm;
            if (m == 0) out[(size_t)(rowb + r) * EDGE_DIM + 16] = a1[r] + b16;
        }
    }
}

extern "C" void kernel_launch(void* const* d_in, const int* in_sizes, int n_in,
                              void* d_out, int out_size, void* d_ws, size_t ws_size,
                              hipStream_t stream) {
    const float* nf  = (const float*)d_in[0];
    const int*   idx = (const int*)d_in[1];
    const float* W1  = (const float*)d_in[2];
    const float* b1  = (const float*)d_in[3];
    const float* g   = (const float*)d_in[4];
    const float* be  = (const float*)d_in[5];
    const float* W2  = (const float*)d_in[6];
    const float* b2  = (const float*)d_in[7];
    float* out = (float*)d_out;

    char* ws = (char*)d_ws;
    __bf16* P       = (__bf16*)ws;
    int*    counts2 = (int*)(ws + 25600000);
    int*    slots   = (int*)(ws + 28800000);
    __bf16* W1F     = (__bf16*)(ws + 41600000);
    __bf16* W2F     = (__bf16*)(ws + 41665536);

    int stride = (in_sizes[1] == 2 * NUM_CONN) ? 1 : 2;

    prep_kernel<<<196, 256, 0, stream>>>(W1, W2, W1F, W2F, counts2);
    front_kernel<<<FRONT_BLOCKS, 256, 0, stream>>>(idx, stride, counts2, slots, nf, W1F, P);
    edge_kernel<<<NUM_EDGES / 16, 256, 0, stream>>>((const uint4*)P, counts2, slots,
                                                    b1, g, be, W2F, b2, out);
}